// Round 1
// baseline (1053.353 us; speedup 1.0000x reference)
//
#include <hip/hip_runtime.h>
#include <math.h>

#define NN 50000
#define NE 800000
#define NEP 850000          // NE + NN self loops
#define FI 1284
#define HD 128
#define NH (NN * HD)        // 6,400,000

// ---------------- helpers ----------------

__device__ __forceinline__ void atomicMaxF(float* addr, float v) {
    // sign-magnitude trick: works for mixed signs, init must be -inf
    if (v >= 0.f) atomicMax((int*)addr, __float_as_int(v));
    else          atomicMin((unsigned int*)addr, __float_as_uint(v));
}

__device__ __forceinline__ float wave_reduce_sum(float v) {
    #pragma unroll
    for (int off = 32; off; off >>= 1) v += __shfl_down(v, off);
    return v;
}

// ---------------- init ----------------

__global__ void k_init(float* out1, float* m1, float* den1,
                       float* m2, float* den2, float* o2a, float* sc) {
    int i = blockIdx.x * blockDim.x + threadIdx.x;
    if (i < NH) out1[i] = 0.f;
    if (i < NN) {
        m1[i]  = -INFINITY; den1[i] = 0.f;
        m2[i]  = -INFINITY; den2[i] = 0.f;
        o2a[i] = 0.f;
    }
    if (i < 8) sc[i] = 0.f;
}

// sum of edge_attr -> sc[0]
__global__ void k_sum_attr(const float* __restrict__ eattr, float* sc) {
    int i = blockIdx.x * blockDim.x + threadIdx.x;
    float v = (i < NE) ? eattr[i] : 0.f;
    v = wave_reduce_sum(v);
    if ((threadIdx.x & 63) == 0) atomicAdd(&sc[0], v);
}

// c1 = dot(We1, att_e1) -> sc[1];  c2 = We2[0]*att_e2[0] -> sc[2]
__global__ void k_consts(const float* We1, const float* ae1,
                         const float* We2, const float* ae2, float* sc) {
    int l = threadIdx.x;  // 64 threads
    float v = We1[l] * ae1[l] + We1[l + 64] * ae1[l + 64];
    v = wave_reduce_sum(v);
    if (l == 0) { sc[1] = v; sc[2] = We2[0] * ae2[0]; }
}

// ---------------- GEMM1: h1 = x @ W1  (fp32, 64x128 tile, BK=16) ----------------

__global__ __launch_bounds__(256) void k_gemm1(const float* __restrict__ x,
                                               const float* __restrict__ W,
                                               float* __restrict__ h1) {
    __shared__ float xs[16][64];    // [k][row]
    __shared__ float ws[16][HD];    // [k][col]
    const int t = threadIdx.x;
    const int row0 = blockIdx.x * 64;
    const int tx = t & 15;          // col group: cols tx*8..+7
    const int ty = t >> 4;          // row group: rows ty*4..+3

    float acc[4][8] = {};

    for (int k0 = 0; k0 < FI; k0 += 16) {
        // stage x tile: thread loads 4 consecutive k for one row (coalesced float4)
        {
            int r  = t & 63;
            int kc = (t >> 6) << 2;          // 0,4,8,12
            int gr = row0 + r;
            int gk = k0 + kc;
            float4 v = make_float4(0.f, 0.f, 0.f, 0.f);
            if (gr < NN) {
                if (gk + 3 < FI) {
                    v = *(const float4*)&x[(size_t)gr * FI + gk];
                } else {
                    if (gk + 0 < FI) v.x = x[(size_t)gr * FI + gk + 0];
                    if (gk + 1 < FI) v.y = x[(size_t)gr * FI + gk + 1];
                    if (gk + 2 < FI) v.z = x[(size_t)gr * FI + gk + 2];
                    if (gk + 3 < FI) v.w = x[(size_t)gr * FI + gk + 3];
                }
            }
            xs[kc + 0][r] = v.x; xs[kc + 1][r] = v.y;
            xs[kc + 2][r] = v.z; xs[kc + 3][r] = v.w;
        }
        // stage W tile: 16x128, float4 per thread x2 (coalesced)
        {
            int kk = t >> 5;                 // 0..7
            int c4 = (t & 31) * 4;
            #pragma unroll
            for (int h = 0; h < 2; ++h, kk += 8) {
                int gk = k0 + kk;
                float4 v = make_float4(0.f, 0.f, 0.f, 0.f);
                if (gk < FI) v = *(const float4*)&W[(size_t)gk * HD + c4];
                *(float4*)&ws[kk][c4] = v;
            }
        }
        __syncthreads();
        #pragma unroll
        for (int kk = 0; kk < 16; ++kk) {
            float4 xv = *(const float4*)&xs[kk][ty * 4];
            float4 wa = *(const float4*)&ws[kk][tx * 8];
            float4 wb = *(const float4*)&ws[kk][tx * 8 + 4];
            float xr[4] = {xv.x, xv.y, xv.z, xv.w};
            float wc[8] = {wa.x, wa.y, wa.z, wa.w, wb.x, wb.y, wb.z, wb.w};
            #pragma unroll
            for (int r = 0; r < 4; ++r)
                #pragma unroll
                for (int c = 0; c < 8; ++c)
                    acc[r][c] += xr[r] * wc[c];
        }
        __syncthreads();
    }
    #pragma unroll
    for (int r = 0; r < 4; ++r) {
        int gr = row0 + ty * 4 + r;
        if (gr < NN) {
            *(float4*)&h1[(size_t)gr * HD + tx * 8]     = make_float4(acc[r][0], acc[r][1], acc[r][2], acc[r][3]);
            *(float4*)&h1[(size_t)gr * HD + tx * 8 + 4] = make_float4(acc[r][4], acc[r][5], acc[r][6], acc[r][7]);
        }
    }
}

// as1[i] = h1[i,:]·att_src1 ; ad1[i] = h1[i,:]·att_dst1  (one wave per node)
__global__ __launch_bounds__(256) void k_rowdot(const float* __restrict__ h1,
                                                const float* __restrict__ asrc,
                                                const float* __restrict__ adst,
                                                float* as1, float* ad1) {
    int wid = threadIdx.x >> 6, l = threadIdx.x & 63;
    int i = blockIdx.x * 4 + wid;
    if (i >= NN) return;
    float2 hv = *(const float2*)&h1[(size_t)i * HD + 2 * l];
    float2 av = *(const float2*)&asrc[2 * l];
    float2 dv = *(const float2*)&adst[2 * l];
    float s = hv.x * av.x + hv.y * av.y;
    float d = hv.x * dv.x + hv.y * dv.y;
    #pragma unroll
    for (int off = 32; off; off >>= 1) {
        s += __shfl_down(s, off);
        d += __shfl_down(d, off);
    }
    if (l == 0) { as1[i] = s; ad1[i] = d; }
}

// ---------------- layer-1 edge passes ----------------

__global__ void k_alpha1(const int* __restrict__ ei, const float* __restrict__ eattr,
                         const float* __restrict__ as1, const float* __restrict__ ad1,
                         const float* __restrict__ sc, float* ea1, float* m1) {
    int e = blockIdx.x * blockDim.x + threadIdx.x;
    if (e >= NEP) return;
    int s, d; float av;
    if (e < NE) { s = ei[e]; d = ei[NE + e]; av = eattr[e]; }
    else        { s = d = e - NE; av = sc[0] * (1.0f / NE); }
    float a = as1[s] + ad1[d] + av * sc[1];
    a = (a > 0.f) ? a : 0.2f * a;
    ea1[e] = a;
    atomicMaxF(&m1[d], a);
}

__global__ void k_exp1(const int* __restrict__ ei, const float* __restrict__ m1,
                       float* ea1, float* den1) {
    int e = blockIdx.x * blockDim.x + threadIdx.x;
    if (e >= NEP) return;
    int d = (e < NE) ? ei[NE + e] : e - NE;
    float v = expf(ea1[e] - m1[d]);
    ea1[e] = v;
    atomicAdd(&den1[d], v);
}

// out1[d,:] += coef * h1[s,:]   (thread per edge-dim, 128 dims)
__global__ __launch_bounds__(256) void k_accum1(const int* __restrict__ ei,
                                                const float* __restrict__ ea1,
                                                const float* __restrict__ den1,
                                                const float* __restrict__ h1,
                                                float* out1) {
    int idx = blockIdx.x * 256 + threadIdx.x;     // < NEP*128 = 108.8M
    int e = idx >> 7;
    int j = idx & 127;
    if (e >= NEP) return;
    int s, d;
    if (e < NE) { s = ei[e]; d = ei[NE + e]; }
    else        { s = d = e - NE; }
    float coef = ea1[e] / (den1[d] + 1e-16f);
    atomicAdd(&out1[(size_t)d * HD + j], coef * h1[(size_t)s * HD + j]);
}

// x2 = elu(out1 + b1); h2[i] = x2[i,:]·W2  (one wave per node; x2 never stored)
__global__ __launch_bounds__(256) void k_l2prep(const float* __restrict__ out1,
                                                const float* __restrict__ b1,
                                                const float* __restrict__ W2,
                                                float* h2) {
    int wid = threadIdx.x >> 6, l = threadIdx.x & 63;
    int i = blockIdx.x * 4 + wid;
    if (i >= NN) return;
    float2 v  = *(const float2*)&out1[(size_t)i * HD + 2 * l];
    float2 bb = *(const float2*)&b1[2 * l];
    float2 w  = *(const float2*)&W2[2 * l];
    float a = v.x + bb.x; a = (a > 0.f) ? a : (expf(a) - 1.f);
    float b = v.y + bb.y; b = (b > 0.f) ? b : (expf(b) - 1.f);
    float p = a * w.x + b * w.y;
    p = wave_reduce_sum(p);
    if (l == 0) h2[i] = p;
}

// ---------------- layer-2 edge passes (scalar features) ----------------

__global__ void k_alpha2(const int* __restrict__ ei, const float* __restrict__ eattr,
                         const float* __restrict__ h2,
                         const float* __restrict__ as2, const float* __restrict__ ad2,
                         const float* __restrict__ sc, float* ea2, float* m2) {
    int e = blockIdx.x * blockDim.x + threadIdx.x;
    if (e >= NEP) return;
    int s, d; float av;
    if (e < NE) { s = ei[e]; d = ei[NE + e]; av = eattr[e]; }
    else        { s = d = e - NE; av = sc[0] * (1.0f / NE); }
    float a = as2[0] * h2[s] + ad2[0] * h2[d] + av * sc[2];
    a = (a > 0.f) ? a : 0.2f * a;
    ea2[e] = a;
    atomicMaxF(&m2[d], a);
}

__global__ void k_exp2(const int* __restrict__ ei, const float* __restrict__ m2,
                       float* ea2, float* den2) {
    int e = blockIdx.x * blockDim.x + threadIdx.x;
    if (e >= NEP) return;
    int d = (e < NE) ? ei[NE + e] : e - NE;
    float v = expf(ea2[e] - m2[d]);
    ea2[e] = v;
    atomicAdd(&den2[d], v);
}

__global__ void k_accum2(const int* __restrict__ ei, const float* __restrict__ ea2,
                         const float* __restrict__ den2, const float* __restrict__ h2,
                         float* o2a) {
    int e = blockIdx.x * blockDim.x + threadIdx.x;
    if (e >= NEP) return;
    int s, d;
    if (e < NE) { s = ei[e]; d = ei[NE + e]; }
    else        { s = d = e - NE; }
    atomicAdd(&o2a[d], ea2[e] / (den2[d] + 1e-16f) * h2[s]);
}

__global__ void k_final(const float* __restrict__ o2a, const float* __restrict__ b2,
                        float* __restrict__ out) {
    int i = blockIdx.x * blockDim.x + threadIdx.x;
    if (i >= NN) return;
    float v = o2a[i] + b2[0];
    out[i] = (v >= 0.f) ? v : 0.01f * v;
}

// ---------------- launch ----------------

extern "C" void kernel_launch(void* const* d_in, const int* in_sizes, int n_in,
                              void* d_out, int out_size, void* d_ws, size_t ws_size,
                              hipStream_t stream) {
    const float* x     = (const float*)d_in[0];
    const int*   ei    = (const int*)d_in[1];     // [2, E] int32
    const float* eattr = (const float*)d_in[2];
    const float* W1    = (const float*)d_in[3];
    const float* asrc1 = (const float*)d_in[4];
    const float* adst1 = (const float*)d_in[5];
    const float* We1   = (const float*)d_in[6];
    const float* ae1   = (const float*)d_in[7];
    const float* b1    = (const float*)d_in[8];
    const float* W2    = (const float*)d_in[9];
    const float* as2   = (const float*)d_in[10];
    const float* ad2   = (const float*)d_in[11];
    const float* We2   = (const float*)d_in[12];
    const float* ae2   = (const float*)d_in[13];
    const float* b2    = (const float*)d_in[14];
    float* out = (float*)d_out;

    float* w    = (float*)d_ws;
    float* h1   = w;                 // NH
    float* out1 = w + (size_t)NH;    // NH
    float* as1  = w + (size_t)2 * NH;
    float* ad1  = as1 + NN;
    float* m1   = ad1 + NN;
    float* den1 = m1 + NN;
    float* h2   = den1 + NN;
    float* m2   = h2 + NN;
    float* den2 = m2 + NN;
    float* o2a  = den2 + NN;
    float* ea1  = o2a + NN;          // NEP
    float* ea2  = ea1 + NEP;         // NEP
    float* sc   = ea2 + NEP;         // 8 scalars: [0]=sum_attr [1]=c1 [2]=c2

    k_init<<<(NH + 255) / 256, 256, 0, stream>>>(out1, m1, den1, m2, den2, o2a, sc);
    k_sum_attr<<<(NE + 255) / 256, 256, 0, stream>>>(eattr, sc);
    k_consts<<<1, 64, 0, stream>>>(We1, ae1, We2, ae2, sc);

    k_gemm1<<<(NN + 63) / 64, 256, 0, stream>>>(x, W1, h1);
    k_rowdot<<<(NN + 3) / 4, 256, 0, stream>>>(h1, asrc1, adst1, as1, ad1);

    k_alpha1<<<(NEP + 255) / 256, 256, 0, stream>>>(ei, eattr, as1, ad1, sc, ea1, m1);
    k_exp1<<<(NEP + 255) / 256, 256, 0, stream>>>(ei, m1, ea1, den1);
    k_accum1<<<(NEP * 128) / 256, 256, 0, stream>>>(ei, ea1, den1, h1, out1);

    k_l2prep<<<(NN + 3) / 4, 256, 0, stream>>>(out1, b1, W2, h2);

    k_alpha2<<<(NEP + 255) / 256, 256, 0, stream>>>(ei, eattr, h2, as2, ad2, sc, ea2, m2);
    k_exp2<<<(NEP + 255) / 256, 256, 0, stream>>>(ei, m2, ea2, den2);
    k_accum2<<<(NEP + 255) / 256, 256, 0, stream>>>(ei, ea2, den2, h2, o2a);

    k_final<<<(NN + 255) / 256, 256, 0, stream>>>(o2a, b2, out);
}

// Round 2
// 841.699 us; speedup vs baseline: 1.2515x; 1.2515x over previous
//
#include <hip/hip_runtime.h>
#include <math.h>

#define NN 50000
#define NE 800000
#define NEP 850000          // NE + NN self loops
#define FI 1284
#define HD 128
#define NH (NN * HD)        // 6,400,000
#define SCAN_B 256
#define NBLK ((NN + SCAN_B - 1) / SCAN_B)   // 196 (<=256)

// ---------------- helpers ----------------

__device__ __forceinline__ void atomicMaxF(float* addr, float v) {
    if (v >= 0.f) atomicMax((int*)addr, __float_as_int(v));
    else          atomicMin((unsigned int*)addr, __float_as_uint(v));
}

__device__ __forceinline__ float wave_reduce_sum(float v) {
    #pragma unroll
    for (int off = 32; off; off >>= 1) v += __shfl_down(v, off);
    return v;
}

// ---------------- init ----------------

__global__ void k_init(float* m1, float* den1, float* m2, float* den2,
                       float* o2a, int* cnt, float* sc) {
    int i = blockIdx.x * blockDim.x + threadIdx.x;
    if (i < NN) {
        m1[i]  = -INFINITY; den1[i] = 0.f;
        m2[i]  = -INFINITY; den2[i] = 0.f;
        o2a[i] = 0.f;
        cnt[i] = 0;
    }
    if (i < 8) sc[i] = 0.f;
}

__global__ void k_sum_attr(const float* __restrict__ eattr, float* sc) {
    int i = blockIdx.x * blockDim.x + threadIdx.x;
    float v = (i < NE) ? eattr[i] : 0.f;
    v = wave_reduce_sum(v);
    if ((threadIdx.x & 63) == 0) atomicAdd(&sc[0], v);
}

__global__ void k_consts(const float* We1, const float* ae1,
                         const float* We2, const float* ae2, float* sc) {
    int l = threadIdx.x;  // 64 threads
    float v = We1[l] * ae1[l] + We1[l + 64] * ae1[l + 64];
    v = wave_reduce_sum(v);
    if (l == 0) { sc[1] = v; sc[2] = We2[0] * ae2[0]; }
}

// ---------------- GEMM1: h1 = x @ W1  (fp32, 64x128 tile, BK=16) ----------------

__global__ __launch_bounds__(256) void k_gemm1(const float* __restrict__ x,
                                               const float* __restrict__ W,
                                               float* __restrict__ h1) {
    __shared__ float xs[16][64];
    __shared__ float ws[16][HD];
    const int t = threadIdx.x;
    const int row0 = blockIdx.x * 64;
    const int tx = t & 15;
    const int ty = t >> 4;

    float acc[4][8] = {};

    for (int k0 = 0; k0 < FI; k0 += 16) {
        {
            int r  = t & 63;
            int kc = (t >> 6) << 2;
            int gr = row0 + r;
            int gk = k0 + kc;
            float4 v = make_float4(0.f, 0.f, 0.f, 0.f);
            if (gr < NN) {
                if (gk + 3 < FI) {
                    v = *(const float4*)&x[(size_t)gr * FI + gk];
                } else {
                    if (gk + 0 < FI) v.x = x[(size_t)gr * FI + gk + 0];
                    if (gk + 1 < FI) v.y = x[(size_t)gr * FI + gk + 1];
                    if (gk + 2 < FI) v.z = x[(size_t)gr * FI + gk + 2];
                    if (gk + 3 < FI) v.w = x[(size_t)gr * FI + gk + 3];
                }
            }
            xs[kc + 0][r] = v.x; xs[kc + 1][r] = v.y;
            xs[kc + 2][r] = v.z; xs[kc + 3][r] = v.w;
        }
        {
            int kk = t >> 5;
            int c4 = (t & 31) * 4;
            #pragma unroll
            for (int h = 0; h < 2; ++h, kk += 8) {
                int gk = k0 + kk;
                float4 v = make_float4(0.f, 0.f, 0.f, 0.f);
                if (gk < FI) v = *(const float4*)&W[(size_t)gk * HD + c4];
                *(float4*)&ws[kk][c4] = v;
            }
        }
        __syncthreads();
        #pragma unroll
        for (int kk = 0; kk < 16; ++kk) {
            float4 xv = *(const float4*)&xs[kk][ty * 4];
            float4 wa = *(const float4*)&ws[kk][tx * 8];
            float4 wb = *(const float4*)&ws[kk][tx * 8 + 4];
            float xr[4] = {xv.x, xv.y, xv.z, xv.w};
            float wc[8] = {wa.x, wa.y, wa.z, wa.w, wb.x, wb.y, wb.z, wb.w};
            #pragma unroll
            for (int r = 0; r < 4; ++r)
                #pragma unroll
                for (int c = 0; c < 8; ++c)
                    acc[r][c] += xr[r] * wc[c];
        }
        __syncthreads();
    }
    #pragma unroll
    for (int r = 0; r < 4; ++r) {
        int gr = row0 + ty * 4 + r;
        if (gr < NN) {
            *(float4*)&h1[(size_t)gr * HD + tx * 8]     = make_float4(acc[r][0], acc[r][1], acc[r][2], acc[r][3]);
            *(float4*)&h1[(size_t)gr * HD + tx * 8 + 4] = make_float4(acc[r][4], acc[r][5], acc[r][6], acc[r][7]);
        }
    }
}

__global__ __launch_bounds__(256) void k_rowdot(const float* __restrict__ h1,
                                                const float* __restrict__ asrc,
                                                const float* __restrict__ adst,
                                                float* as1, float* ad1) {
    int wid = threadIdx.x >> 6, l = threadIdx.x & 63;
    int i = blockIdx.x * 4 + wid;
    if (i >= NN) return;
    float2 hv = *(const float2*)&h1[(size_t)i * HD + 2 * l];
    float2 av = *(const float2*)&asrc[2 * l];
    float2 dv = *(const float2*)&adst[2 * l];
    float s = hv.x * av.x + hv.y * av.y;
    float d = hv.x * dv.x + hv.y * dv.y;
    #pragma unroll
    for (int off = 32; off; off >>= 1) {
        s += __shfl_down(s, off);
        d += __shfl_down(d, off);
    }
    if (l == 0) { as1[i] = s; ad1[i] = d; }
}

// ---------------- layer-1 edge passes ----------------

// alpha + per-dst max + dst histogram
__global__ void k_alpha1(const int* __restrict__ ei, const float* __restrict__ eattr,
                         const float* __restrict__ as1, const float* __restrict__ ad1,
                         const float* __restrict__ sc, float* ea1, float* m1, int* cnt) {
    int e = blockIdx.x * blockDim.x + threadIdx.x;
    if (e >= NEP) return;
    int s, d; float av;
    if (e < NE) { s = ei[e]; d = ei[NE + e]; av = eattr[e]; }
    else        { s = d = e - NE; av = sc[0] * (1.0f / NE); }
    float a = as1[s] + ad1[d] + av * sc[1];
    a = (a > 0.f) ? a : 0.2f * a;
    ea1[e] = a;
    atomicMaxF(&m1[d], a);
    atomicAdd(&cnt[d], 1);
}

// ---------------- exclusive scan of cnt -> start (3 kernels) ----------------

__global__ void k_scan_blk(const int* __restrict__ cnt, int* incl, int* bsum) {
    __shared__ int sh[SCAN_B];
    int i = blockIdx.x * SCAN_B + threadIdx.x;
    sh[threadIdx.x] = (i < NN) ? cnt[i] : 0;
    __syncthreads();
    for (int off = 1; off < SCAN_B; off <<= 1) {
        int t = (threadIdx.x >= off) ? sh[threadIdx.x - off] : 0;
        __syncthreads();
        sh[threadIdx.x] += t;
        __syncthreads();
    }
    if (i < NN) incl[i] = sh[threadIdx.x];
    if (threadIdx.x == SCAN_B - 1) bsum[blockIdx.x] = sh[threadIdx.x];
}

__global__ void k_scan_top(int* bsum) {
    __shared__ int sh[SCAN_B];
    sh[threadIdx.x] = (threadIdx.x < NBLK) ? bsum[threadIdx.x] : 0;
    __syncthreads();
    for (int off = 1; off < SCAN_B; off <<= 1) {
        int t = (threadIdx.x >= off) ? sh[threadIdx.x - off] : 0;
        __syncthreads();
        sh[threadIdx.x] += t;
        __syncthreads();
    }
    if (threadIdx.x < NBLK) bsum[threadIdx.x] = sh[threadIdx.x];
}

// start[i] = incl[i]-cnt[i]+blockoff (in-place on incl ok), cursor=start
__global__ void k_scan_fix(int* incl_start, const int* __restrict__ cnt,
                           const int* __restrict__ bsum, int* cursor) {
    int i = blockIdx.x * SCAN_B + threadIdx.x;
    if (i >= NN) return;
    int off = (blockIdx.x > 0) ? bsum[blockIdx.x - 1] : 0;
    int st = incl_start[i] - cnt[i] + off;
    incl_start[i] = st;
    cursor[i] = st;
}

// exp + denom + CSR placement
__global__ void k_exp1(const int* __restrict__ ei, const float* __restrict__ m1,
                       const float* __restrict__ ea1, float* den1,
                       int* cursor, int* csr_src, float* csr_val) {
    int e = blockIdx.x * blockDim.x + threadIdx.x;
    if (e >= NEP) return;
    int s, d;
    if (e < NE) { s = ei[e]; d = ei[NE + e]; }
    else        { s = d = e - NE; }
    float v = expf(ea1[e] - m1[d]);
    atomicAdd(&den1[d], v);
    int pos = atomicAdd(&cursor[d], 1);
    csr_src[pos] = s;
    csr_val[pos] = v;
}

// gather-accumulate: one wave per dst node, float2 per lane = 128 dims
__global__ __launch_bounds__(256) void k_accum1_csr(const int* __restrict__ csr_src,
                                                    const float* __restrict__ csr_val,
                                                    const int* __restrict__ start,
                                                    const int* __restrict__ cnt,
                                                    const float* __restrict__ den1,
                                                    const float* __restrict__ h1,
                                                    float* __restrict__ out1) {
    int wid = threadIdx.x >> 6, l = threadIdx.x & 63;
    int d = blockIdx.x * 4 + wid;
    if (d >= NN) return;
    int s0 = start[d], n = cnt[d];
    float inv = 1.f / (den1[d] + 1e-16f);
    float ax = 0.f, ay = 0.f;
    for (int i = 0; i < n; ++i) {
        int s = csr_src[s0 + i];
        float c = csr_val[s0 + i] * inv;
        float2 hv = *(const float2*)&h1[(size_t)s * HD + 2 * l];
        ax += c * hv.x; ay += c * hv.y;
    }
    *(float2*)&out1[(size_t)d * HD + 2 * l] = make_float2(ax, ay);
}

// x2 = elu(out1 + b1); h2[i] = x2[i,:]·W2
__global__ __launch_bounds__(256) void k_l2prep(const float* __restrict__ out1,
                                                const float* __restrict__ b1,
                                                const float* __restrict__ W2,
                                                float* h2) {
    int wid = threadIdx.x >> 6, l = threadIdx.x & 63;
    int i = blockIdx.x * 4 + wid;
    if (i >= NN) return;
    float2 v  = *(const float2*)&out1[(size_t)i * HD + 2 * l];
    float2 bb = *(const float2*)&b1[2 * l];
    float2 w  = *(const float2*)&W2[2 * l];
    float a = v.x + bb.x; a = (a > 0.f) ? a : (expf(a) - 1.f);
    float b = v.y + bb.y; b = (b > 0.f) ? b : (expf(b) - 1.f);
    float p = a * w.x + b * w.y;
    p = wave_reduce_sum(p);
    if (l == 0) h2[i] = p;
}

// ---------------- layer-2 edge passes (scalar features) ----------------

__global__ void k_alpha2(const int* __restrict__ ei, const float* __restrict__ eattr,
                         const float* __restrict__ h2,
                         const float* __restrict__ as2, const float* __restrict__ ad2,
                         const float* __restrict__ sc, float* ea2, float* m2) {
    int e = blockIdx.x * blockDim.x + threadIdx.x;
    if (e >= NEP) return;
    int s, d; float av;
    if (e < NE) { s = ei[e]; d = ei[NE + e]; av = eattr[e]; }
    else        { s = d = e - NE; av = sc[0] * (1.0f / NE); }
    float a = as2[0] * h2[s] + ad2[0] * h2[d] + av * sc[2];
    a = (a > 0.f) ? a : 0.2f * a;
    ea2[e] = a;
    atomicMaxF(&m2[d], a);
}

__global__ void k_exp2(const int* __restrict__ ei, const float* __restrict__ m2,
                       float* ea2, float* den2) {
    int e = blockIdx.x * blockDim.x + threadIdx.x;
    if (e >= NEP) return;
    int d = (e < NE) ? ei[NE + e] : e - NE;
    float v = expf(ea2[e] - m2[d]);
    ea2[e] = v;
    atomicAdd(&den2[d], v);
}

__global__ void k_accum2(const int* __restrict__ ei, const float* __restrict__ ea2,
                         const float* __restrict__ den2, const float* __restrict__ h2,
                         float* o2a) {
    int e = blockIdx.x * blockDim.x + threadIdx.x;
    if (e >= NEP) return;
    int s, d;
    if (e < NE) { s = ei[e]; d = ei[NE + e]; }
    else        { s = d = e - NE; }
    atomicAdd(&o2a[d], ea2[e] / (den2[d] + 1e-16f) * h2[s]);
}

__global__ void k_final(const float* __restrict__ o2a, const float* __restrict__ b2,
                        float* __restrict__ out) {
    int i = blockIdx.x * blockDim.x + threadIdx.x;
    if (i >= NN) return;
    float v = o2a[i] + b2[0];
    out[i] = (v >= 0.f) ? v : 0.01f * v;
}

// ---------------- launch ----------------

extern "C" void kernel_launch(void* const* d_in, const int* in_sizes, int n_in,
                              void* d_out, int out_size, void* d_ws, size_t ws_size,
                              hipStream_t stream) {
    const float* x     = (const float*)d_in[0];
    const int*   ei    = (const int*)d_in[1];
    const float* eattr = (const float*)d_in[2];
    const float* W1    = (const float*)d_in[3];
    const float* asrc1 = (const float*)d_in[4];
    const float* adst1 = (const float*)d_in[5];
    const float* We1   = (const float*)d_in[6];
    const float* ae1   = (const float*)d_in[7];
    const float* b1    = (const float*)d_in[8];
    const float* W2    = (const float*)d_in[9];
    const float* as2   = (const float*)d_in[10];
    const float* ad2   = (const float*)d_in[11];
    const float* We2   = (const float*)d_in[12];
    const float* ae2   = (const float*)d_in[13];
    const float* b2    = (const float*)d_in[14];
    float* out = (float*)d_out;

    float* w    = (float*)d_ws;
    float* h1   = w;                      // NH
    float* out1 = w + (size_t)NH;         // NH
    float* as1  = w + (size_t)2 * NH;     // NN
    float* ad1  = as1 + NN;
    float* m1   = ad1 + NN;
    float* den1 = m1 + NN;
    float* h2   = den1 + NN;
    float* m2   = h2 + NN;
    float* den2 = m2 + NN;
    float* o2a  = den2 + NN;
    float* ea1  = o2a + NN;               // NEP (alpha, layer1)
    float* csr_val = ea1 + NEP;           // NEP (also reused as ea2 in layer 2)
    float* ea2  = csr_val;                //   alias: free after accum1
    float* sc   = csr_val + NEP;          // 8 scalars
    int*   cnt    = (int*)(sc + 8);       // NN
    int*   start  = cnt + NN;             // NN (incl during scan, then start)
    int*   cursor = start + NN;           // NN
    int*   bsum   = cursor + NN;          // 256
    int*   csr_src = bsum + 256;          // NEP

    k_init<<<(NN + 255) / 256, 256, 0, stream>>>(m1, den1, m2, den2, o2a, cnt, sc);
    k_sum_attr<<<(NE + 255) / 256, 256, 0, stream>>>(eattr, sc);
    k_consts<<<1, 64, 0, stream>>>(We1, ae1, We2, ae2, sc);

    k_gemm1<<<(NN + 63) / 64, 256, 0, stream>>>(x, W1, h1);
    k_rowdot<<<(NN + 3) / 4, 256, 0, stream>>>(h1, asrc1, adst1, as1, ad1);

    k_alpha1<<<(NEP + 255) / 256, 256, 0, stream>>>(ei, eattr, as1, ad1, sc, ea1, m1, cnt);
    k_scan_blk<<<NBLK, SCAN_B, 0, stream>>>(cnt, start, bsum);
    k_scan_top<<<1, SCAN_B, 0, stream>>>(bsum);
    k_scan_fix<<<NBLK, SCAN_B, 0, stream>>>(start, cnt, bsum, cursor);
    k_exp1<<<(NEP + 255) / 256, 256, 0, stream>>>(ei, m1, ea1, den1, cursor, csr_src, csr_val);
    k_accum1_csr<<<(NN + 3) / 4, 256, 0, stream>>>(csr_src, csr_val, start, cnt, den1, h1, out1);

    k_l2prep<<<(NN + 3) / 4, 256, 0, stream>>>(out1, b1, W2, h2);

    k_alpha2<<<(NEP + 255) / 256, 256, 0, stream>>>(ei, eattr, h2, as2, ad2, sc, ea2, m2);
    k_exp2<<<(NEP + 255) / 256, 256, 0, stream>>>(ei, m2, ea2, den2);
    k_accum2<<<(NEP + 255) / 256, 256, 0, stream>>>(ei, ea2, den2, h2, o2a);

    k_final<<<(NN + 255) / 256, 256, 0, stream>>>(o2a, b2, out);
}

// Round 4
// 780.147 us; speedup vs baseline: 1.3502x; 1.0789x over previous
//
#include <hip/hip_runtime.h>
#include <math.h>

#define NN 50000
#define NE 800000
#define NEP 850000          // NE + NN self loops
#define FI 1284
#define HD 128
#define KP 1312             // FI padded to 41*32 for MFMA K-loop
#define NH (NN * HD)        // 6,400,000
#define SCAN_B 256
#define NBLK ((NN + SCAN_B - 1) / SCAN_B)   // 196 (<=256)

typedef float f32x4 __attribute__((ext_vector_type(4)));
typedef short bfrag __attribute__((ext_vector_type(8)));   // 8 bf16 in 4 VGPRs

// ---------------- helpers ----------------

__device__ __forceinline__ void atomicMaxF(float* addr, float v) {
    if (v >= 0.f) atomicMax((int*)addr, __float_as_int(v));
    else          atomicMin((unsigned int*)addr, __float_as_uint(v));
}

__device__ __forceinline__ float wave_reduce_sum(float v) {
    #pragma unroll
    for (int off = 32; off; off >>= 1) v += __shfl_down(v, off);
    return v;
}

__device__ __forceinline__ ushort f2bf(float f) {   // RNE fp32->bf16 bits
    unsigned u = __float_as_uint(f);
    u += 0x7FFFu + ((u >> 16) & 1u);
    return (ushort)(u >> 16);
}

// ---------------- init ----------------

__global__ void k_init(float* m1, float* den1, float* m2, float* den2,
                       float* o2a, int* cnt, float* sc) {
    int i = blockIdx.x * blockDim.x + threadIdx.x;
    if (i < NN) {
        m1[i]  = -INFINITY; den1[i] = 0.f;
        m2[i]  = -INFINITY; den2[i] = 0.f;
        o2a[i] = 0.f;
        cnt[i] = 0;
    }
    if (i < 8) sc[i] = 0.f;
}

__global__ void k_sum_attr(const float* __restrict__ eattr, float* sc) {
    int i = blockIdx.x * blockDim.x + threadIdx.x;
    float v = (i < NE) ? eattr[i] : 0.f;
    v = wave_reduce_sum(v);
    if ((threadIdx.x & 63) == 0) atomicAdd(&sc[0], v);
}

__global__ void k_consts(const float* We1, const float* ae1,
                         const float* We2, const float* ae2, float* sc) {
    int l = threadIdx.x;  // 64 threads
    float v = We1[l] * ae1[l] + We1[l + 64] * ae1[l + 64];
    v = wave_reduce_sum(v);
    if (l == 0) { sc[1] = v; sc[2] = We2[0] * ae2[0]; }
}

// Wt[c][k] = bf16(W1[k][c]), K-padded with zeros to KP
__global__ void k_wt(const float* __restrict__ W, ushort* __restrict__ Wt) {
    int i = blockIdx.x * 256 + threadIdx.x;
    if (i >= HD * KP) return;
    int c = i / KP, k = i % KP;
    float v = (k < FI) ? W[(size_t)k * HD + c] : 0.f;
    Wt[i] = f2bf(v);
}

// ---------------- GEMM1: h1 = x @ W1  (bf16 MFMA, fp32 acc, no LDS) ----------------

__global__ __launch_bounds__(256) void k_gemm1_mfma(const float* __restrict__ x,
                                                    const ushort* __restrict__ Wt,
                                                    float* __restrict__ h1) {
    const int t = threadIdx.x;
    const int wid = t >> 6, l = t & 63;
    const int lr = l & 15, lg = l >> 4;
    const int row0 = blockIdx.x * 64 + wid * 16;

    int rowc = row0 + lr; if (rowc > NN - 1) rowc = NN - 1;   // clamp OOB loads
    const float*  ap = x  + (size_t)rowc * FI + lg * 8;
    const ushort* bp = Wt + (size_t)lr * KP + lg * 8;

    f32x4 acc[8];
    #pragma unroll
    for (int c = 0; c < 8; ++c) acc[c] = (f32x4){0.f, 0.f, 0.f, 0.f};

    #pragma unroll 2
    for (int k0 = 0; k0 < 1280; k0 += 32) {
        float4 a0 = *(const float4*)(ap + k0);
        float4 a1 = *(const float4*)(ap + k0 + 4);
        bfrag af;
        af[0] = (short)f2bf(a0.x); af[1] = (short)f2bf(a0.y);
        af[2] = (short)f2bf(a0.z); af[3] = (short)f2bf(a0.w);
        af[4] = (short)f2bf(a1.x); af[5] = (short)f2bf(a1.y);
        af[6] = (short)f2bf(a1.z); af[7] = (short)f2bf(a1.w);
        #pragma unroll
        for (int cg = 0; cg < 8; ++cg) {
            bfrag bf = *(const bfrag*)(bp + (size_t)cg * 16 * KP + k0);
            acc[cg] = __builtin_amdgcn_mfma_f32_16x16x32_bf16(af, bf, acc[cg], 0, 0, 0);
        }
    }
    {   // K tail: k0 = 1280, valid k < 1284 only (lg==0 low half); Wt is zero-padded
        float4 a0 = make_float4(0.f, 0.f, 0.f, 0.f);
        if (lg == 0) a0 = *(const float4*)(ap + 1280);
        bfrag af;
        af[0] = (short)f2bf(a0.x); af[1] = (short)f2bf(a0.y);
        af[2] = (short)f2bf(a0.z); af[3] = (short)f2bf(a0.w);
        af[4] = 0; af[5] = 0; af[6] = 0; af[7] = 0;
        #pragma unroll
        for (int cg = 0; cg < 8; ++cg) {
            bfrag bf = *(const bfrag*)(bp + (size_t)cg * 16 * KP + 1280);
            acc[cg] = __builtin_amdgcn_mfma_f32_16x16x32_bf16(af, bf, acc[cg], 0, 0, 0);
        }
    }

    #pragma unroll
    for (int cg = 0; cg < 8; ++cg) {
        #pragma unroll
        for (int r = 0; r < 4; ++r) {
            int gr = row0 + lg * 4 + r;
            if (gr < NN) h1[(size_t)gr * HD + cg * 16 + lr] = acc[cg][r];
        }
    }
}

__global__ __launch_bounds__(256) void k_rowdot(const float* __restrict__ h1,
                                                const float* __restrict__ asrc,
                                                const float* __restrict__ adst,
                                                float* as1, float* ad1) {
    int wid = threadIdx.x >> 6, l = threadIdx.x & 63;
    int i = blockIdx.x * 4 + wid;
    if (i >= NN) return;
    float2 hv = *(const float2*)&h1[(size_t)i * HD + 2 * l];
    float2 av = *(const float2*)&asrc[2 * l];
    float2 dv = *(const float2*)&adst[2 * l];
    float s = hv.x * av.x + hv.y * av.y;
    float d = hv.x * dv.x + hv.y * dv.y;
    #pragma unroll
    for (int off = 32; off; off >>= 1) {
        s += __shfl_down(s, off);
        d += __shfl_down(d, off);
    }
    if (l == 0) { as1[i] = s; ad1[i] = d; }
}

// ---------------- layer-1 edge passes ----------------

__global__ void k_alpha1(const int* __restrict__ ei, const float* __restrict__ eattr,
                         const float* __restrict__ as1, const float* __restrict__ ad1,
                         const float* __restrict__ sc, float* ea1, float* m1, int* cnt) {
    int e = blockIdx.x * blockDim.x + threadIdx.x;
    if (e >= NEP) return;
    int s, d; float av;
    if (e < NE) { s = ei[e]; d = ei[NE + e]; av = eattr[e]; }
    else        { s = d = e - NE; av = sc[0] * (1.0f / NE); }
    float a = as1[s] + ad1[d] + av * sc[1];
    a = (a > 0.f) ? a : 0.2f * a;
    ea1[e] = a;
    atomicMaxF(&m1[d], a);
    atomicAdd(&cnt[d], 1);
}

// ---------------- exclusive scan of cnt -> start ----------------

__global__ void k_scan_blk(const int* __restrict__ cnt, int* incl, int* bsum) {
    __shared__ int sh[SCAN_B];
    int i = blockIdx.x * SCAN_B + threadIdx.x;
    sh[threadIdx.x] = (i < NN) ? cnt[i] : 0;
    __syncthreads();
    for (int off = 1; off < SCAN_B; off <<= 1) {
        int t = (threadIdx.x >= off) ? sh[threadIdx.x - off] : 0;
        __syncthreads();
        sh[threadIdx.x] += t;
        __syncthreads();
    }
    if (i < NN) incl[i] = sh[threadIdx.x];
    if (threadIdx.x == SCAN_B - 1) bsum[blockIdx.x] = sh[threadIdx.x];
}

__global__ void k_scan_top(int* bsum) {
    __shared__ int sh[SCAN_B];
    sh[threadIdx.x] = (threadIdx.x < NBLK) ? bsum[threadIdx.x] : 0;
    __syncthreads();
    for (int off = 1; off < SCAN_B; off <<= 1) {
        int t = (threadIdx.x >= off) ? sh[threadIdx.x - off] : 0;
        __syncthreads();
        sh[threadIdx.x] += t;
        __syncthreads();
    }
    if (threadIdx.x < NBLK) bsum[threadIdx.x] = sh[threadIdx.x];
}

__global__ void k_scan_fix(int* incl_start, const int* __restrict__ cnt,
                           const int* __restrict__ bsum, int* cursor) {
    int i = blockIdx.x * SCAN_B + threadIdx.x;
    if (i >= NN) return;
    int off = (blockIdx.x > 0) ? bsum[blockIdx.x - 1] : 0;
    int st = incl_start[i] - cnt[i] + off;
    incl_start[i] = st;
    cursor[i] = st;
}

__global__ void k_exp1(const int* __restrict__ ei, const float* __restrict__ m1,
                       const float* __restrict__ ea1, float* den1,
                       int* cursor, int* csr_src, float* csr_val) {
    int e = blockIdx.x * blockDim.x + threadIdx.x;
    if (e >= NEP) return;
    int s, d;
    if (e < NE) { s = ei[e]; d = ei[NE + e]; }
    else        { s = d = e - NE; }
    float v = expf(ea1[e] - m1[d]);
    atomicAdd(&den1[d], v);
    int pos = atomicAdd(&cursor[d], 1);
    csr_src[pos] = s;
    csr_val[pos] = v;
}

// gather-accumulate + fused ELU/bias/W2-dot epilogue (out1 never materialized):
// one wave per dst node; lanes hold dims 2l, 2l+1; h2[d] = sum_j elu(out1[d,j]+b1[j])*W2[j]
__global__ __launch_bounds__(256) void k_accum1_csr(const int* __restrict__ csr_src,
                                                    const float* __restrict__ csr_val,
                                                    const int* __restrict__ start,
                                                    const int* __restrict__ cnt,
                                                    const float* __restrict__ den1,
                                                    const float* __restrict__ h1,
                                                    const float* __restrict__ b1,
                                                    const float* __restrict__ W2,
                                                    float* __restrict__ h2) {
    int wid = threadIdx.x >> 6, l = threadIdx.x & 63;
    int d = blockIdx.x * 4 + wid;
    if (d >= NN) return;
    int s0 = start[d], n = cnt[d];
    float inv = 1.f / (den1[d] + 1e-16f);
    float ax = 0.f, ay = 0.f;
    for (int i = 0; i < n; ++i) {
        int s = csr_src[s0 + i];
        float c = csr_val[s0 + i] * inv;
        float2 hv = *(const float2*)&h1[(size_t)s * HD + 2 * l];
        ax += c * hv.x; ay += c * hv.y;
    }
    float2 bb = *(const float2*)&b1[2 * l];
    float2 w  = *(const float2*)&W2[2 * l];
    float a = ax + bb.x; a = (a > 0.f) ? a : (expf(a) - 1.f);
    float b = ay + bb.y; b = (b > 0.f) ? b : (expf(b) - 1.f);
    float p = a * w.x + b * w.y;
    p = wave_reduce_sum(p);
    if (l == 0) h2[d] = p;
}

// ---------------- layer-2 edge passes ----------------

__global__ void k_alpha2(const int* __restrict__ ei, const float* __restrict__ eattr,
                         const float* __restrict__ h2,
                         const float* __restrict__ as2, const float* __restrict__ ad2,
                         const float* __restrict__ sc, float* ea2, float* m2) {
    int e = blockIdx.x * blockDim.x + threadIdx.x;
    if (e >= NEP) return;
    int s, d; float av;
    if (e < NE) { s = ei[e]; d = ei[NE + e]; av = eattr[e]; }
    else        { s = d = e - NE; av = sc[0] * (1.0f / NE); }
    float a = as2[0] * h2[s] + ad2[0] * h2[d] + av * sc[2];
    a = (a > 0.f) ? a : 0.2f * a;
    ea2[e] = a;
    atomicMaxF(&m2[d], a);
}

__global__ void k_exp2(const int* __restrict__ ei, const float* __restrict__ m2,
                       float* ea2, float* den2) {
    int e = blockIdx.x * blockDim.x + threadIdx.x;
    if (e >= NEP) return;
    int d = (e < NE) ? ei[NE + e] : e - NE;
    float v = expf(ea2[e] - m2[d]);
    ea2[e] = v;
    atomicAdd(&den2[d], v);
}

__global__ void k_accum2(const int* __restrict__ ei, const float* __restrict__ ea2,
                         const float* __restrict__ den2, const float* __restrict__ h2,
                         float* o2a) {
    int e = blockIdx.x * blockDim.x + threadIdx.x;
    if (e >= NEP) return;
    int s, d;
    if (e < NE) { s = ei[e]; d = ei[NE + e]; }
    else        { s = d = e - NE; }
    atomicAdd(&o2a[d], ea2[e] / (den2[d] + 1e-16f) * h2[s]);
}

__global__ void k_final(const float* __restrict__ o2a, const float* __restrict__ b2,
                        float* __restrict__ out) {
    int i = blockIdx.x * blockDim.x + threadIdx.x;
    if (i >= NN) return;
    float v = o2a[i] + b2[0];
    out[i] = (v >= 0.f) ? v : 0.01f * v;
}

// ---------------- launch ----------------

extern "C" void kernel_launch(void* const* d_in, const int* in_sizes, int n_in,
                              void* d_out, int out_size, void* d_ws, size_t ws_size,
                              hipStream_t stream) {
    const float* x     = (const float*)d_in[0];
    const int*   ei    = (const int*)d_in[1];
    const float* eattr = (const float*)d_in[2];
    const float* W1    = (const float*)d_in[3];
    const float* asrc1 = (const float*)d_in[4];
    const float* adst1 = (const float*)d_in[5];
    const float* We1   = (const float*)d_in[6];
    const float* ae1   = (const float*)d_in[7];
    const float* b1    = (const float*)d_in[8];
    const float* W2    = (const float*)d_in[9];
    const float* as2   = (const float*)d_in[10];
    const float* ad2   = (const float*)d_in[11];
    const float* We2   = (const float*)d_in[12];
    const float* ae2   = (const float*)d_in[13];
    const float* b2    = (const float*)d_in[14];
    float* out = (float*)d_out;

    // workspace layout (total ~38.3 MB, well under the R1/R2-proven footprint)
    float* w    = (float*)d_ws;
    float* h1   = w;                      // NH
    float* as1  = w + (size_t)NH;         // NN
    float* ad1  = as1 + NN;
    float* m1   = ad1 + NN;
    float* den1 = m1 + NN;
    float* h2   = den1 + NN;
    float* m2   = h2 + NN;
    float* den2 = m2 + NN;
    float* o2a  = den2 + NN;
    float* ea1  = o2a + NN;               // NEP
    float* csr_val = ea1 + NEP;           // NEP (reused as ea2 in layer 2)
    float* ea2  = csr_val;
    float* sc   = csr_val + NEP;          // 8 scalars
    int*   cnt    = (int*)(sc + 8);       // NN
    int*   start  = cnt + NN;             // NN
    int*   cursor = start + NN;           // NN
    int*   bsum   = cursor + NN;          // 256
    int*   csr_src = bsum + 256;          // NEP
    ushort* Wt   = (ushort*)(csr_src + NEP);  // HD*KP bf16

    k_init<<<(NN + 255) / 256, 256, 0, stream>>>(m1, den1, m2, den2, o2a, cnt, sc);
    k_sum_attr<<<(NE + 255) / 256, 256, 0, stream>>>(eattr, sc);
    k_consts<<<1, 64, 0, stream>>>(We1, ae1, We2, ae2, sc);
    k_wt<<<(HD * KP + 255) / 256, 256, 0, stream>>>(W1, Wt);

    k_gemm1_mfma<<<(NN + 63) / 64, 256, 0, stream>>>(x, Wt, h1);
    k_rowdot<<<(NN + 3) / 4, 256, 0, stream>>>(h1, asrc1, adst1, as1, ad1);

    k_alpha1<<<(NEP + 255) / 256, 256, 0, stream>>>(ei, eattr, as1, ad1, sc, ea1, m1, cnt);
    k_scan_blk<<<NBLK, SCAN_B, 0, stream>>>(cnt, start, bsum);
    k_scan_top<<<1, SCAN_B, 0, stream>>>(bsum);
    k_scan_fix<<<NBLK, SCAN_B, 0, stream>>>(start, cnt, bsum, cursor);
    k_exp1<<<(NEP + 255) / 256, 256, 0, stream>>>(ei, m1, ea1, den1, cursor, csr_src, csr_val);
    k_accum1_csr<<<(NN + 3) / 4, 256, 0, stream>>>(csr_src, csr_val, start, cnt, den1, h1, b1, W2, h2);

    k_alpha2<<<(NEP + 255) / 256, 256, 0, stream>>>(ei, eattr, h2, as2, ad2, sc, ea2, m2);
    k_exp2<<<(NEP + 255) / 256, 256, 0, stream>>>(ei, m2, ea2, den2);
    k_accum2<<<(NEP + 255) / 256, 256, 0, stream>>>(ei, ea2, den2, h2, o2a);

    k_final<<<(NN + 255) / 256, 256, 0, stream>>>(o2a, b2, out);
}